// Round 4
// baseline (394.474 us; speedup 1.0000x reference)
//
#include <hip/hip_runtime.h>
#include <cstdint>

// LSTM cell: B=8192, DIM_IN=1024, DIM_OUT=1024, d=2048
// gates = [X|H][8192,2048] @ W[2048,4096] + b ; epilogue fused into GEMM.
// R3: BK=32 (64B LDS row stride -> free 2-way bank aliasing; BK=64's 128B
// stride tripled conflicts), single-barrier double-buffered K-loop
// (prefetch k+1 before compute k so the vmcnt(0) barrier drain overlaps
// a full MFMA phase), preps merged into one kernel.
// W pre-permuted: n'' = (j>>4)*64 + g*16 + (j&15) so each wave's 64 cols =
// 16 j-columns x all 4 gates (in-register LSTM epilogue, gates never hit HBM).

#define B_ROWS 8192
#define DK 2048
#define DOUT 1024
#define TM 128
#define TN 128
#define BK 32

typedef __bf16 bf16x8 __attribute__((ext_vector_type(8)));
typedef __bf16 bf16x4 __attribute__((ext_vector_type(4)));
typedef float f32x4 __attribute__((ext_vector_type(4)));

__device__ inline void load16_to_lds(const __bf16* gsrc, __bf16* ldst) {
    __builtin_amdgcn_global_load_lds(
        (const __attribute__((address_space(1))) void*)gsrc,
        (__attribute__((address_space(3))) void*)ldst,
        16, 0, 0);
}

__device__ inline float fast_sigmoid(float x) {
    return __builtin_amdgcn_rcpf(1.0f + __builtin_amdgcn_exp2f(-1.442695041f * x));
}
__device__ inline float fast_tanh(float x) {
    return 1.0f - 2.0f * __builtin_amdgcn_rcpf(1.0f + __builtin_amdgcn_exp2f(2.885390082f * x));
}

// ---- merged prep: blocks [0,8192) cast X; blocks [8192,9216) permute W ----
// prep_x: X = bf16(concat(x,h)) [8192][2048]; 8 elems/thread, 16B writes.
// prep_w: Wt[n''][k] = bf16(W_g[k][j]); n'' = (j>>4)*64 + g*16 + (j&15).
__global__ __launch_bounds__(256) void prep_all(
    const float* __restrict__ x, const float* __restrict__ h,
    const float* __restrict__ WI, const float* __restrict__ WF,
    const float* __restrict__ WG, const float* __restrict__ WO,
    __bf16* __restrict__ X, __bf16* __restrict__ Wt)
{
    __shared__ float tile[64][33];
    int bid = blockIdx.x;
    int t = threadIdx.x;
    if (bid < 8192) {
        int id = bid * 256 + t;
        int b = id >> 8;
        int k = (id & 255) * 8;   // multiple of 8: never straddles 1024
        const float* src = (k < 1024) ? &x[(size_t)b * 1024 + k]
                                      : &h[(size_t)b * 1024 + (k - 1024)];
        float4 v0 = *(const float4*)src;
        float4 v1 = *(const float4*)(src + 4);
        bf16x8 o = { (__bf16)v0.x, (__bf16)v0.y, (__bf16)v0.z, (__bf16)v0.w,
                     (__bf16)v1.x, (__bf16)v1.y, (__bf16)v1.z, (__bf16)v1.w };
        *(bf16x8*)&X[(size_t)b * 2048 + k] = o;
    } else {
        int wb = bid - 8192;
        int kb = wb >> 5;          // 0..31 (k tiles of 64)
        int jb = wb & 31;          // 0..31 (j tiles of 32)
        int j0 = jb * 32;
        int tx = t & 31, ty = t >> 5;   // (32,8)
        const float* Ws[4] = {WI, WF, WG, WO};
#pragma unroll
        for (int g = 0; g < 4; ++g) {
            const float* W = Ws[g];
#pragma unroll
            for (int yy = 0; yy < 64; yy += 8) {
                int k = kb * 64 + ty + yy;
                tile[ty + yy][tx] = W[(size_t)k * 1024 + j0 + tx];
            }
            __syncthreads();
#pragma unroll
            for (int w = 0; w < 2; ++w) {
                int slot = w * 256 + t;       // 0..511
                int r = slot >> 4;            // j within tile, 0..31
                int k0 = (slot & 15) * 4;     // k offset within 64
                bf16x4 o = { (__bf16)tile[k0 + 0][r], (__bf16)tile[k0 + 1][r],
                             (__bf16)tile[k0 + 2][r], (__bf16)tile[k0 + 3][r] };
                int npp = (jb * 2 + (r >> 4)) * 64 + g * 16 + (r & 15);
                *(bf16x4*)&Wt[(size_t)npp * 2048 + kb * 64 + k0] = o;
            }
            __syncthreads();
        }
    }
}

// ---- fused GEMM + LSTM epilogue, double-buffered single-barrier K-loop ----
__global__ __launch_bounds__(256) void lstm_gemm(
    const __bf16* __restrict__ Xbf, const __bf16* __restrict__ Wt,
    const float* __restrict__ c,
    const float* __restrict__ bI, const float* __restrict__ bF,
    const float* __restrict__ bG, const float* __restrict__ bO,
    float* __restrict__ outH, float* __restrict__ outC)
{
    __shared__ __bf16 As[2][TM * BK];   // 2 x 8 KB
    __shared__ __bf16 Bs[2][TN * BK];   // 2 x 8 KB

    const int t = threadIdx.x;
    const int lane = t & 63;
    const int wave = t >> 6;
    const int wm = wave >> 1;         // 2x2 waves of 64x64
    const int wn = wave & 1;
    const int m0 = blockIdx.x * TM;   // 64 blocks in M
    const int nb = blockIdx.y;        // 32 blocks in N
    const int n0 = nb * TN;

    f32x4 acc[4][4];
#pragma unroll
    for (int i = 0; i < 4; ++i)
#pragma unroll
        for (int j = 0; j < 4; ++j) acc[i][j] = (f32x4){0.f, 0.f, 0.f, 0.f};

    // staging: chunk ci = q*256 + t ; row = ci>>2 ; kc = (ci&3)*8
    const int r0 = t >> 2, kc0 = (t & 3) * 8;
    const __bf16* gA0 = Xbf + (size_t)(m0 + r0) * DK + kc0;
    const __bf16* gA1 = Xbf + (size_t)(m0 + 64 + r0) * DK + kc0;
    const __bf16* gB0 = Wt + (size_t)(n0 + r0) * DK + kc0;
    const __bf16* gB1 = Wt + (size_t)(n0 + 64 + r0) * DK + kc0;
    // wave-uniform LDS bases (HW adds lane*16 bytes)
    const int l0 = wave * 512;          // chunk group q=0
    const int l1 = 2048 + wave * 512;   // chunk group q=1

    const int lr = lane & 15;
    const int kh = (lane >> 4) * 8;
    const int arow = wm * 64 + lr;
    const int brow = wn * 64 + lr;

    // prologue: prefetch k-tile 0 into buffer 0
    load16_to_lds(gA0, &As[0][l0]);
    load16_to_lds(gA1, &As[0][l1]);
    load16_to_lds(gB0, &Bs[0][l0]);
    load16_to_lds(gB1, &Bs[0][l1]);
    gA0 += BK; gA1 += BK; gB0 += BK; gB1 += BK;

    for (int kk = 0; kk < DK / BK; ++kk) {
        __syncthreads();   // drains vmcnt(0): buf[kk&1] ready; prev reads done
        if (kk < DK / BK - 1) {
            const int nb2 = (kk + 1) & 1;
            load16_to_lds(gA0, &As[nb2][l0]);
            load16_to_lds(gA1, &As[nb2][l1]);
            load16_to_lds(gB0, &Bs[nb2][l0]);
            load16_to_lds(gB1, &Bs[nb2][l1]);
            gA0 += BK; gA1 += BK; gB0 += BK; gB1 += BK;
        }
        const int cb = kk & 1;
        bf16x8 a[4], b[4];
#pragma unroll
        for (int i = 0; i < 4; ++i)
            a[i] = *(const bf16x8*)&As[cb][(arow + i * 16) * BK + kh];
#pragma unroll
        for (int j = 0; j < 4; ++j)
            b[j] = *(const bf16x8*)&Bs[cb][(brow + j * 16) * BK + kh];
#pragma unroll
        for (int i = 0; i < 4; ++i)
#pragma unroll
            for (int j = 0; j < 4; ++j)
                acc[i][j] = __builtin_amdgcn_mfma_f32_16x16x32_bf16(a[i], b[j], acc[i][j], 0, 0, 0);
    }

    // epilogue: C/D layout col=lane&15, row=(lane>>4)*4+reg; acc[i][g] = gate g
    const int col = lane & 15;
    const int j = (nb * 2 + wn) * 16 + col;     // original gate column
    const float biI = bI[j], biF = bF[j], biG = bG[j], biO = bO[j];
    const int rbase = m0 + wm * 64 + (lane >> 4) * 4;
#pragma unroll
    for (int i = 0; i < 4; ++i) {
#pragma unroll
        for (int r = 0; r < 4; ++r) {
            int row = rbase + i * 16 + r;
            float I = fast_sigmoid(acc[i][0][r] + biI);
            float F = fast_sigmoid(acc[i][1][r] + biF);
            float G = fast_tanh(acc[i][2][r] + biG);
            float O = fast_sigmoid(acc[i][3][r] + biO);
            size_t idx = (size_t)row * DOUT + j;
            float Cn = F * c[idx] + I * G;
            outH[idx] = O * fast_tanh(Cn);
            outC[idx] = Cn;
        }
    }
}

extern "C" void kernel_launch(void* const* d_in, const int* in_sizes, int n_in,
                              void* d_out, int out_size, void* d_ws, size_t ws_size,
                              hipStream_t stream) {
    const float* x  = (const float*)d_in[0];
    const float* h  = (const float*)d_in[1];
    const float* c  = (const float*)d_in[2];
    const float* WI = (const float*)d_in[3];
    const float* bI = (const float*)d_in[4];
    const float* WF = (const float*)d_in[5];
    const float* bF = (const float*)d_in[6];
    const float* WG = (const float*)d_in[7];
    const float* bG = (const float*)d_in[8];
    const float* WO = (const float*)d_in[9];
    const float* bO = (const float*)d_in[10];

    __bf16* Xbf = (__bf16*)d_ws;                                    // 32 MB
    __bf16* Wt  = (__bf16*)((char*)d_ws + (size_t)B_ROWS * DK * 2); // 16 MB
    float* outH = (float*)d_out;
    float* outC = outH + (size_t)B_ROWS * DOUT;

    prep_all<<<8192 + 1024, 256, 0, stream>>>(x, h, WI, WF, WG, WO, Xbf, Wt);
    lstm_gemm<<<dim3(B_ROWS / TM, 4 * DOUT / TN), 256, 0, stream>>>(
        Xbf, Wt, c, bI, bF, bG, bO, outH, outC);
}